// Round 11
// baseline (300.723 us; speedup 1.0000x reference)
//
#include <hip/hip_runtime.h>
#include <stdint.h>

typedef _Float16 half8 __attribute__((ext_vector_type(8)));
typedef _Float16 half4v __attribute__((ext_vector_type(4)));
typedef float floatx4 __attribute__((ext_vector_type(4)));
typedef float floatx16 __attribute__((ext_vector_type(16)));

#define TT 4096
#define DH 512

#define WAITLGKM() asm volatile("s_waitcnt lgkmcnt(0)" ::: "memory")
#define BAR() __builtin_amdgcn_s_barrier()
#define FENCE() asm volatile("" ::: "memory")

__device__ __forceinline__ unsigned short f2h(float f) {
    union { _Float16 h; unsigned short u; } v;
    v.h = (_Float16)f;
    return v.u;
}

// ---------- kernel 1: normalize right half of x -> xn (fp16), one wave per row ----------
__global__ void norm_k(const float* __restrict__ x, unsigned short* __restrict__ xn) {
    const int w = threadIdx.x >> 6, l = threadIdx.x & 63;
    const int row = blockIdx.x * 4 + w;              // 0 .. B*T-1
    const float* src = x + (size_t)row * 1024 + 512 + l * 8;
    floatx4 a = *(const floatx4*)src;
    floatx4 c = *(const floatx4*)(src + 4);
    float s = a[0]*a[0] + a[1]*a[1] + a[2]*a[2] + a[3]*a[3]
            + c[0]*c[0] + c[1]*c[1] + c[2]*c[2] + c[3]*c[3];
    #pragma unroll
    for (int off = 32; off > 0; off >>= 1) s += __shfl_xor(s, off);
    const float scale = 1.0f / fmaxf(sqrtf(s), 1e-12f);
    float v[8] = {a[0], a[1], a[2], a[3], c[0], c[1], c[2], c[3]};
    uint32_t pk[4];
    #pragma unroll
    for (int i = 0; i < 4; i++)
        pk[i] = (uint32_t)f2h(v[2*i] * scale) | ((uint32_t)f2h(v[2*i+1] * scale) << 16);
    uint4 o; o.x = pk[0]; o.y = pk[1]; o.z = pk[2]; o.w = pk[3];
    *(uint4*)(xn + (size_t)row * DH + l * 8) = o;
}

// ---------- kernel 2: xnT[b][d][t] = xn[b][t][d], 64x64 LDS tile transpose ----------
__global__ void transpose_k(const unsigned short* __restrict__ xn,
                            unsigned short* __restrict__ xnT) {
    __shared__ __align__(16) unsigned short tile[64 * 72];  // +8 pad
    const int b = blockIdx.z;
    const int t0 = blockIdx.x * 64, d0 = blockIdx.y * 64;
    const int tid = threadIdx.x;
    #pragma unroll
    for (int i = 0; i < 2; i++) {
        int c = i * 256 + tid;
        int tr = c >> 3, d8 = c & 7;
        uint4 vv = *(const uint4*)(xn + ((size_t)(b * TT + t0 + tr) * DH + d0 + d8 * 8));
        *(uint4*)&tile[tr * 72 + d8 * 8] = vv;
    }
    __syncthreads();
    #pragma unroll
    for (int i = 0; i < 2; i++) {
        int c = i * 256 + tid;
        int dd = c >> 3, t8 = c & 7;
        uint32_t pk[4];
        #pragma unroll
        for (int k = 0; k < 4; k++) {
            uint32_t h0 = tile[(t8 * 8 + 2 * k    ) * 72 + dd];
            uint32_t h1 = tile[(t8 * 8 + 2 * k + 1) * 72 + dd];
            pk[k] = h0 | (h1 << 16);
        }
        uint4 o; o.x = pk[0]; o.y = pk[1]; o.z = pk[2]; o.w = pk[3];
        *(uint4*)(xnT + ((size_t)(b * DH + d0 + dd) * TT + t0 + t8 * 8)) = o;
    }
}

// ---------- kernel 3: homogeneous 8-wave fused kernel (R6 schedule, kt in registers) ----------
// Wave w: step1 role (g=w>>2, mi=(w>>1)&1, dh=w&1): S^T partial p=g*2+dh over K=128;
//         step3/epilogue role: d-slice [w*64, w*64+64), kt fragments in REGISTERS.
// Per tile t (3 barriers):
//   vmcnt(10) [kn[t] landed; V+bf stay in flight]
//   step1 (8 LDS rd, 16 mfma) ; Sred writes ; lgkm ; BAR_B
//   restage kn[t+1] (gll, wave-private) ; reduce (4 LDS rd) ; vmcnt(0) [V,bf landed]
//   *V ; issue V[t+1] ; W write (chunk-XOR) ; lgkm ; BAR_C
//   step3 (8 W rd from LDS, bf from regs, 16 mfma) ; issue bf[t+1] ; BAR_D
// LDS 104 KiB: kn[8w][32][128] 64K | Sred[4][64][64] 32K | W[64][64] 8K (c^(row&7) swizzle).
__global__ __launch_bounds__(512, 2) void fused_k(
    const unsigned short* __restrict__ xn, const unsigned short* __restrict__ xnT,
    const float* __restrict__ V, const float* __restrict__ bias,
    const float* __restrict__ x, float* __restrict__ out)
{
    __shared__ __align__(16) unsigned short smem[53248];   // 104 KiB
    unsigned short* knB   = smem;            // [8 w][32 kk][128 d], chunk16 ^ (row&7)
    unsigned short* SredL = smem + 32768;    // [4 p][64 q][64 kk], unit4 ^ ((q&7)<<1)
    unsigned short* Wl    = smem + 49152;    // [64 q][64 kk], chunk16 c stored at c^(q&7)

    const int tid = threadIdx.x;
    const int w = tid >> 6, l = tid & 63;
    const int h = l >> 5, m32 = l & 31;
    const int g = w >> 2, mi = (w >> 1) & 1, dh = w & 1;
    const int p = g * 2 + dh;
    const int wk0 = g * 256 + dh * 128;      // step1 k-range base
    const int wd0 = w * 64;                  // step3 d-slice base

    // XCD-aware swizzle
    const int flat = blockIdx.y * 64 + blockIdx.x;
    const int work = (flat & 7) * 32 + (flat >> 3);
    const int b = work >> 6, qt = work & 63;
    const int q0 = qt * 64;

    const unsigned short* xnb = xn  + (size_t)b * TT * DH;
    const unsigned short* xtb = xnT + (size_t)b * DH * TT;

    unsigned short* knP = knB + w * 4096;

    // reduce-phase mapping: q-row tq, kk chunk to
    const int tq = tid >> 3, to = tid & 7;
    const float* vptr = V + (size_t)(q0 + tq) * TT + to * 8;
    const int rsw = ((to * 2) ^ ((tq & 7) << 1)) * 4;   // Sred phys unit offset (u16)
    const int wwc = (to ^ (tq & 7)) * 8;                // W write chunk offset (u16)

    // ---- prologue: Q fragments (B-operand): lane q=q0+ni*32+m32, k=wk0+ks*16+h*8+j
    half8 qf[2][8];
    #pragma unroll
    for (int ni = 0; ni < 2; ni++)
        #pragma unroll
        for (int ks = 0; ks < 8; ks++)
            qf[ni][ks] = *(const half8*)(xnb + (size_t)(q0 + ni*32 + m32) * DH
                                         + wk0 + ks*16 + h*8);
    FENCE();
    // stage kn[0]: 8 gll, 4 rows each
    #pragma unroll
    for (int i = 0; i < 8; i++) {
        int r = i * 4 + (l >> 4);                        // local kk row 0..31
        int c = (l & 15) ^ (r & 7);                      // pre-swizzled global chunk
        const unsigned short* gp = xnb + (size_t)(mi*32 + r) * DH + wk0 + c * 8;
        __builtin_amdgcn_global_load_lds(
            (const __attribute__((address_space(1))) void*)gp,
            (__attribute__((address_space(3))) void*)&knP[i * 512], 16, 0, 0);
    }
    FENCE();
    // V[0] (2 loads)
    floatx4 vfc0 = *(const floatx4*)(vptr);
    floatx4 vfc1 = *(const floatx4*)(vptr + 4);
    FENCE();
    // bf[0]: kt B-fragments in registers: lane d = wd0+nd*32+m32, kk = ks*16+h*8+j
    half8 bf[2][4];
    #pragma unroll
    for (int nd = 0; nd < 2; nd++)
        #pragma unroll
        for (int ks = 0; ks < 4; ks++)
            bf[nd][ks] = *(const half8*)(xtb + (size_t)(wd0 + nd*32 + m32) * TT
                                         + ks*16 + h*8);
    FENCE();

    floatx16 acc[2][2];
    #pragma unroll
    for (int i = 0; i < 2; i++)
        #pragma unroll
        for (int j = 0; j < 2; j++)
            acc[i][j] = (floatx16)(0.f);

    #pragma unroll 1
    for (int t = 0; t < 64; t++) {
        // ---- kn[t] landed (V[t] 2 + bf[t] 8 stay in flight) ----
        asm volatile("s_waitcnt vmcnt(10)" ::: "memory");

        // ---- step1: S^T partial p, rows mi, K=128; 8 reads, 16 mfma ----
        floatx16 s0 = (floatx16)(0.f), s1 = (floatx16)(0.f);
        __builtin_amdgcn_s_setprio(1);
        #pragma unroll
        for (int ks = 0; ks < 8; ks++) {
            half8 a = *(const half8*)&knP[m32 * 128 + (((ks*2 + h) ^ (m32 & 7)) * 8)];
            s0 = __builtin_amdgcn_mfma_f32_32x32x16_f16(a, qf[0][ks], s0, 0, 0, 0);
            s1 = __builtin_amdgcn_mfma_f32_32x32x16_f16(a, qf[1][ks], s1, 0, 0, 0);
        }
        __builtin_amdgcn_s_setprio(0);

        // ---- Sred write: [p][q][phys unit], unit4 ^ ((q&7)<<1) ----
        #pragma unroll
        for (int ni = 0; ni < 2; ni++) {
            const int q = ni * 32 + m32;
            unsigned short* sp = SredL + p * 4096 + q * 64;
            const int sw = (q & 7) << 1;
            #pragma unroll
            for (int rr = 0; rr < 4; rr++) {
                int u = (mi * 8 + rr * 2 + h) ^ sw;
                half4v v4;
                if (ni == 0) {
                    v4[0]=(_Float16)s0[rr*4+0]; v4[1]=(_Float16)s0[rr*4+1];
                    v4[2]=(_Float16)s0[rr*4+2]; v4[3]=(_Float16)s0[rr*4+3];
                } else {
                    v4[0]=(_Float16)s1[rr*4+0]; v4[1]=(_Float16)s1[rr*4+1];
                    v4[2]=(_Float16)s1[rr*4+2]; v4[3]=(_Float16)s1[rr*4+3];
                }
                *(half4v*)&sp[u * 4] = v4;
            }
        }
        WAITLGKM();
        BAR();   // BAR_B: Sred complete, step1 kn reads consumed

        // ---- restage kn[t+1] (wave-private slice; lands during next vmcnt(10) cover) ----
        if (t < 63) {
            #pragma unroll
            for (int i = 0; i < 8; i++) {
                int r = i * 4 + (l >> 4);
                int c = (l & 15) ^ (r & 7);
                const unsigned short* gp = xnb + (size_t)((t+1)*64 + mi*32 + r) * DH + wk0 + c * 8;
                __builtin_amdgcn_global_load_lds(
                    (const __attribute__((address_space(1))) void*)gp,
                    (__attribute__((address_space(3))) void*)&knP[i * 512], 16, 0, 0);
            }
            FENCE();
        }

        // ---- reduce: 4 partials (fp16 adds) ----
        half8 pr0 = *(const half8*)&SredL[        tq * 64 + rsw];
        half8 pr1 = *(const half8*)&SredL[4096  + tq * 64 + rsw];
        half8 pr2 = *(const half8*)&SredL[8192  + tq * 64 + rsw];
        half8 pr3 = *(const half8*)&SredL[12288 + tq * 64 + rsw];
        half8 sum = (pr0 + pr1) + (pr2 + pr3);
        asm volatile("s_waitcnt vmcnt(0)" ::: "memory");   // V[t] + bf[t] landed
        half8 wv;
        wv[0]=(_Float16)((float)sum[0]*vfc0[0]); wv[1]=(_Float16)((float)sum[1]*vfc0[1]);
        wv[2]=(_Float16)((float)sum[2]*vfc0[2]); wv[3]=(_Float16)((float)sum[3]*vfc0[3]);
        wv[4]=(_Float16)((float)sum[4]*vfc1[0]); wv[5]=(_Float16)((float)sum[5]*vfc1[1]);
        wv[6]=(_Float16)((float)sum[6]*vfc1[2]); wv[7]=(_Float16)((float)sum[7]*vfc1[3]);
        // ---- issue V[t+1] straight into vfc (last use was above; cover to reduce[t+1]) ----
        if (t < 63) {
            FENCE();
            vfc0 = *(const floatx4*)(vptr + (t+1)*64);
            vfc1 = *(const floatx4*)(vptr + (t+1)*64 + 4);
            FENCE();
        }
        // ---- W write: [q=tq][chunk to stored at to^(tq&7)] ----
        *(half8*)&Wl[tq * 64 + wwc] = wv;
        WAITLGKM();
        BAR();   // BAR_C: W ready; Sred reads consumed

        // ---- step3: ctx[q][wd0..+64] += W * Kn ; W from LDS (8 rd), kt from regs ----
        __builtin_amdgcn_s_setprio(1);
        #pragma unroll
        for (int ks = 0; ks < 4; ks++) {
            const int wc = ((ks*2 + h) ^ (m32 & 7)) * 8;
            half8 wf0 = *(const half8*)&Wl[(m32     ) * 64 + wc];
            half8 wf1 = *(const half8*)&Wl[(32 + m32) * 64 + wc];
            acc[0][0] = __builtin_amdgcn_mfma_f32_32x32x16_f16(wf0, bf[0][ks], acc[0][0], 0, 0, 0);
            acc[0][1] = __builtin_amdgcn_mfma_f32_32x32x16_f16(wf0, bf[1][ks], acc[0][1], 0, 0, 0);
            acc[1][0] = __builtin_amdgcn_mfma_f32_32x32x16_f16(wf1, bf[0][ks], acc[1][0], 0, 0, 0);
            acc[1][1] = __builtin_amdgcn_mfma_f32_32x32x16_f16(wf1, bf[1][ks], acc[1][1], 0, 0, 0);
        }
        __builtin_amdgcn_s_setprio(0);

        // ---- issue bf[t+1] (regs free now; cover to reduce[t+1] vmcnt(0)) ----
        if (t < 63) {
            FENCE();
            #pragma unroll
            for (int nd = 0; nd < 2; nd++)
                #pragma unroll
                for (int ks = 0; ks < 4; ks++)
                    bf[nd][ks] = *(const half8*)(xtb + (size_t)(wd0 + nd*32 + m32) * TT
                                                 + (t+1)*64 + ks*16 + h*8);
            FENCE();
        }
        WAITLGKM();
        BAR();   // BAR_D: step3 W reads consumed -> Sred/W writable next tile
    }

    // ---- epilogue: out = x_left * sigmoid(ctx + bias) ----
    const float* xb = x + (size_t)b * TT * 1024;
    float* ob = out + (size_t)b * TT * DH;
    #pragma unroll
    for (int mi2 = 0; mi2 < 2; mi2++)
        #pragma unroll
        for (int nd = 0; nd < 2; nd++) {
            int d = wd0 + nd * 32 + m32;
            float bv = bias[d];
            #pragma unroll
            for (int r = 0; r < 16; r++) {
                int q = q0 + mi2 * 32 + (r & 3) + 8 * (r >> 2) + 4 * h;
                float cv = acc[mi2][nd][r] + bv;
                float gate = 1.0f / (1.0f + __expf(-cv));
                ob[(size_t)q * DH + d] = xb[(size_t)q * 1024 + d] * gate;
            }
        }
}

extern "C" void kernel_launch(void* const* d_in, const int* in_sizes, int n_in,
                              void* d_out, int out_size, void* d_ws, size_t ws_size,
                              hipStream_t stream) {
    const float* x    = (const float*)d_in[0];
    const float* V    = (const float*)d_in[1];
    const float* bias = (const float*)d_in[2];
    float* out = (float*)d_out;

    unsigned short* xn  = (unsigned short*)d_ws;              // [4][4096][512] fp16
    unsigned short* xnT = xn + (size_t)4 * TT * DH;           // [4][512][4096] fp16

    norm_k<<<dim3(4 * TT / 4), 256, 0, stream>>>(x, xn);
    transpose_k<<<dim3(TT / 64, DH / 64, 4), 256, 0, stream>>>(xn, xnT);
    fused_k<<<dim3(TT / 64, 4), 512, 0, stream>>>(xn, xnT, V, bias, x, out);
}

// Round 12
// 280.476 us; speedup vs baseline: 1.0722x; 1.0722x over previous
//
#include <hip/hip_runtime.h>
#include <stdint.h>

typedef _Float16 half8 __attribute__((ext_vector_type(8)));
typedef _Float16 half4v __attribute__((ext_vector_type(4)));
typedef float floatx4 __attribute__((ext_vector_type(4)));
typedef float floatx16 __attribute__((ext_vector_type(16)));

#define TT 4096
#define DH 512

#define WAITLGKM() asm volatile("s_waitcnt lgkmcnt(0)" ::: "memory")
#define BAR() __builtin_amdgcn_s_barrier()
#define FENCE() asm volatile("" ::: "memory")

__device__ __forceinline__ unsigned short f2h(float f) {
    union { _Float16 h; unsigned short u; } v;
    v.h = (_Float16)f;
    return v.u;
}

// ---------- kernel 1: normalize right half of x -> xn (fp16), one wave per row ----------
__global__ void norm_k(const float* __restrict__ x, unsigned short* __restrict__ xn) {
    const int w = threadIdx.x >> 6, l = threadIdx.x & 63;
    const int row = blockIdx.x * 4 + w;              // 0 .. B*T-1
    const float* src = x + (size_t)row * 1024 + 512 + l * 8;
    floatx4 a = *(const floatx4*)src;
    floatx4 c = *(const floatx4*)(src + 4);
    float s = a[0]*a[0] + a[1]*a[1] + a[2]*a[2] + a[3]*a[3]
            + c[0]*c[0] + c[1]*c[1] + c[2]*c[2] + c[3]*c[3];
    #pragma unroll
    for (int off = 32; off > 0; off >>= 1) s += __shfl_xor(s, off);
    const float scale = 1.0f / fmaxf(sqrtf(s), 1e-12f);
    float v[8] = {a[0], a[1], a[2], a[3], c[0], c[1], c[2], c[3]};
    uint32_t pk[4];
    #pragma unroll
    for (int i = 0; i < 4; i++)
        pk[i] = (uint32_t)f2h(v[2*i] * scale) | ((uint32_t)f2h(v[2*i+1] * scale) << 16);
    uint4 o; o.x = pk[0]; o.y = pk[1]; o.z = pk[2]; o.w = pk[3];
    *(uint4*)(xn + (size_t)row * DH + l * 8) = o;
}

// ---------- kernel 2: xnT[b][d][t] = xn[b][t][d], 64x64 LDS tile transpose ----------
__global__ void transpose_k(const unsigned short* __restrict__ xn,
                            unsigned short* __restrict__ xnT) {
    __shared__ __align__(16) unsigned short tile[64 * 72];  // +8 pad
    const int b = blockIdx.z;
    const int t0 = blockIdx.x * 64, d0 = blockIdx.y * 64;
    const int tid = threadIdx.x;
    #pragma unroll
    for (int i = 0; i < 2; i++) {
        int c = i * 256 + tid;
        int tr = c >> 3, d8 = c & 7;
        uint4 vv = *(const uint4*)(xn + ((size_t)(b * TT + t0 + tr) * DH + d0 + d8 * 8));
        *(uint4*)&tile[tr * 72 + d8 * 8] = vv;
    }
    __syncthreads();
    #pragma unroll
    for (int i = 0; i < 2; i++) {
        int c = i * 256 + tid;
        int dd = c >> 3, t8 = c & 7;
        uint32_t pk[4];
        #pragma unroll
        for (int k = 0; k < 4; k++) {
            uint32_t h0 = tile[(t8 * 8 + 2 * k    ) * 72 + dd];
            uint32_t h1 = tile[(t8 * 8 + 2 * k + 1) * 72 + dd];
            pk[k] = h0 | (h1 << 16);
        }
        uint4 o; o.x = pk[0]; o.y = pk[1]; o.z = pk[2]; o.w = pk[3];
        *(uint4*)(xnT + ((size_t)(b * DH + d0 + dd) * TT + t0 + t8 * 8)) = o;
    }
}

// ---------- kernel 3: homogeneous 8-wave fused kernel (R6 schedule, kt in registers) ----------
// Wave w: step1 role (g=w>>2, mi=(w>>1)&1, dh=w&1): S^T partial p=g*2+dh over K=128;
//         step3/epilogue role: d-slice [w*64, w*64+64), kt fragments in REGISTERS.
// Per tile t (3 barriers):
//   vmcnt(10) [kn[t] landed; V[t]+bf[t] stay in flight]
//   step1 (8 LDS rd, 16 mfma) ; Sred writes ; lgkm ; BAR_B
//   restage kn[t+1] (gll, wave-private) ; reduce (4 LDS rd)
//   [NO manual vmcnt here — compiler emits counted waits for V (vmcnt~16) and bf
//    (vmcnt~8) register uses, leaving kn[t+1] in flight. R11's manual vmcnt(0)
//    drained kn[t+1] too -> per-tile stall; that was the 300us regression.]
//   *V ; issue V[t+1] ; W write (chunk-XOR) ; lgkm ; BAR_C
//   step3 (8 W rd from LDS, bf from regs, 16 mfma) ; issue bf[t+1] ; BAR_D
// LDS 104 KiB: kn[8w][32][128] 64K | Sred[4][64][64] 32K | W[64][64] 8K (c^(q&7) swizzle).
__global__ __launch_bounds__(512, 2) void fused_k(
    const unsigned short* __restrict__ xn, const unsigned short* __restrict__ xnT,
    const float* __restrict__ V, const float* __restrict__ bias,
    const float* __restrict__ x, float* __restrict__ out)
{
    __shared__ __align__(16) unsigned short smem[53248];   // 104 KiB
    unsigned short* knB   = smem;            // [8 w][32 kk][128 d], chunk16 ^ (row&7)
    unsigned short* SredL = smem + 32768;    // [4 p][64 q][64 kk], unit4 ^ ((q&7)<<1)
    unsigned short* Wl    = smem + 49152;    // [64 q][64 kk], chunk16 c stored at c^(q&7)

    const int tid = threadIdx.x;
    const int w = tid >> 6, l = tid & 63;
    const int h = l >> 5, m32 = l & 31;
    const int g = w >> 2, mi = (w >> 1) & 1, dh = w & 1;
    const int p = g * 2 + dh;
    const int wk0 = g * 256 + dh * 128;      // step1 k-range base
    const int wd0 = w * 64;                  // step3 d-slice base

    // XCD-aware swizzle
    const int flat = blockIdx.y * 64 + blockIdx.x;
    const int work = (flat & 7) * 32 + (flat >> 3);
    const int b = work >> 6, qt = work & 63;
    const int q0 = qt * 64;

    const unsigned short* xnb = xn  + (size_t)b * TT * DH;
    const unsigned short* xtb = xnT + (size_t)b * DH * TT;

    unsigned short* knP = knB + w * 4096;

    // reduce-phase mapping: q-row tq, kk chunk to
    const int tq = tid >> 3, to = tid & 7;
    const float* vptr = V + (size_t)(q0 + tq) * TT + to * 8;
    const int rsw = ((to * 2) ^ ((tq & 7) << 1)) * 4;   // Sred phys unit offset (u16)
    const int wwc = (to ^ (tq & 7)) * 8;                // W write chunk offset (u16)

    // ---- prologue: Q fragments (B-operand): lane q=q0+ni*32+m32, k=wk0+ks*16+h*8+j
    half8 qf[2][8];
    #pragma unroll
    for (int ni = 0; ni < 2; ni++)
        #pragma unroll
        for (int ks = 0; ks < 8; ks++)
            qf[ni][ks] = *(const half8*)(xnb + (size_t)(q0 + ni*32 + m32) * DH
                                         + wk0 + ks*16 + h*8);
    FENCE();
    // stage kn[0]: 8 gll, 4 rows each
    #pragma unroll
    for (int i = 0; i < 8; i++) {
        int r = i * 4 + (l >> 4);                        // local kk row 0..31
        int c = (l & 15) ^ (r & 7);                      // pre-swizzled global chunk
        const unsigned short* gp = xnb + (size_t)(mi*32 + r) * DH + wk0 + c * 8;
        __builtin_amdgcn_global_load_lds(
            (const __attribute__((address_space(1))) void*)gp,
            (__attribute__((address_space(3))) void*)&knP[i * 512], 16, 0, 0);
    }
    FENCE();
    // V[0] (2 loads)
    floatx4 vfc0 = *(const floatx4*)(vptr);
    floatx4 vfc1 = *(const floatx4*)(vptr + 4);
    FENCE();
    // bf[0]: kt B-fragments in registers: lane d = wd0+nd*32+m32, kk = ks*16+h*8+j
    half8 bf[2][4];
    #pragma unroll
    for (int nd = 0; nd < 2; nd++)
        #pragma unroll
        for (int ks = 0; ks < 4; ks++)
            bf[nd][ks] = *(const half8*)(xtb + (size_t)(wd0 + nd*32 + m32) * TT
                                         + ks*16 + h*8);
    FENCE();

    floatx16 acc[2][2];
    #pragma unroll
    for (int i = 0; i < 2; i++)
        #pragma unroll
        for (int j = 0; j < 2; j++)
            acc[i][j] = (floatx16)(0.f);

    #pragma unroll 1
    for (int t = 0; t < 64; t++) {
        // ---- kn[t] landed (V[t] 2 + bf[t] 8 stay in flight) ----
        asm volatile("s_waitcnt vmcnt(10)" ::: "memory");

        // ---- step1: S^T partial p, rows mi, K=128; 8 reads, 16 mfma ----
        floatx16 s0 = (floatx16)(0.f), s1 = (floatx16)(0.f);
        __builtin_amdgcn_s_setprio(1);
        #pragma unroll
        for (int ks = 0; ks < 8; ks++) {
            half8 a = *(const half8*)&knP[m32 * 128 + (((ks*2 + h) ^ (m32 & 7)) * 8)];
            s0 = __builtin_amdgcn_mfma_f32_32x32x16_f16(a, qf[0][ks], s0, 0, 0, 0);
            s1 = __builtin_amdgcn_mfma_f32_32x32x16_f16(a, qf[1][ks], s1, 0, 0, 0);
        }
        __builtin_amdgcn_s_setprio(0);

        // ---- Sred write: [p][q][phys unit], unit4 ^ ((q&7)<<1) ----
        #pragma unroll
        for (int ni = 0; ni < 2; ni++) {
            const int q = ni * 32 + m32;
            unsigned short* sp = SredL + p * 4096 + q * 64;
            const int sw = (q & 7) << 1;
            #pragma unroll
            for (int rr = 0; rr < 4; rr++) {
                int u = (mi * 8 + rr * 2 + h) ^ sw;
                half4v v4;
                if (ni == 0) {
                    v4[0]=(_Float16)s0[rr*4+0]; v4[1]=(_Float16)s0[rr*4+1];
                    v4[2]=(_Float16)s0[rr*4+2]; v4[3]=(_Float16)s0[rr*4+3];
                } else {
                    v4[0]=(_Float16)s1[rr*4+0]; v4[1]=(_Float16)s1[rr*4+1];
                    v4[2]=(_Float16)s1[rr*4+2]; v4[3]=(_Float16)s1[rr*4+3];
                }
                *(half4v*)&sp[u * 4] = v4;
            }
        }
        WAITLGKM();
        BAR();   // BAR_B: Sred complete, step1 kn reads consumed

        // ---- restage kn[t+1] (wave-private slice; in flight until next tile's vmcnt(10)) ----
        if (t < 63) {
            #pragma unroll
            for (int i = 0; i < 8; i++) {
                int r = i * 4 + (l >> 4);
                int c = (l & 15) ^ (r & 7);
                const unsigned short* gp = xnb + (size_t)((t+1)*64 + mi*32 + r) * DH + wk0 + c * 8;
                __builtin_amdgcn_global_load_lds(
                    (const __attribute__((address_space(1))) void*)gp,
                    (__attribute__((address_space(3))) void*)&knP[i * 512], 16, 0, 0);
            }
            FENCE();
        }

        // ---- reduce: 4 partials (fp16 adds); compiler emits counted vmcnt for vfc/bf ----
        half8 pr0 = *(const half8*)&SredL[        tq * 64 + rsw];
        half8 pr1 = *(const half8*)&SredL[4096  + tq * 64 + rsw];
        half8 pr2 = *(const half8*)&SredL[8192  + tq * 64 + rsw];
        half8 pr3 = *(const half8*)&SredL[12288 + tq * 64 + rsw];
        half8 sum = (pr0 + pr1) + (pr2 + pr3);
        half8 wv;
        wv[0]=(_Float16)((float)sum[0]*vfc0[0]); wv[1]=(_Float16)((float)sum[1]*vfc0[1]);
        wv[2]=(_Float16)((float)sum[2]*vfc0[2]); wv[3]=(_Float16)((float)sum[3]*vfc0[3]);
        wv[4]=(_Float16)((float)sum[4]*vfc1[0]); wv[5]=(_Float16)((float)sum[5]*vfc1[1]);
        wv[6]=(_Float16)((float)sum[6]*vfc1[2]); wv[7]=(_Float16)((float)sum[7]*vfc1[3]);
        // ---- issue V[t+1] straight into vfc (last use was above; cover to reduce[t+1]) ----
        if (t < 63) {
            FENCE();
            vfc0 = *(const floatx4*)(vptr + (t+1)*64);
            vfc1 = *(const floatx4*)(vptr + (t+1)*64 + 4);
            FENCE();
        }
        // ---- W write: [q=tq][chunk to stored at to^(tq&7)] ----
        *(half8*)&Wl[tq * 64 + wwc] = wv;
        WAITLGKM();
        BAR();   // BAR_C: W ready; Sred reads consumed

        // ---- step3: ctx[q][wd0..+64] += W * Kn ; W from LDS (8 rd), kt from regs ----
        __builtin_amdgcn_s_setprio(1);
        #pragma unroll
        for (int ks = 0; ks < 4; ks++) {
            const int wc = ((ks*2 + h) ^ (m32 & 7)) * 8;
            half8 wf0 = *(const half8*)&Wl[(m32     ) * 64 + wc];
            half8 wf1 = *(const half8*)&Wl[(32 + m32) * 64 + wc];
            acc[0][0] = __builtin_amdgcn_mfma_f32_32x32x16_f16(wf0, bf[0][ks], acc[0][0], 0, 0, 0);
            acc[0][1] = __builtin_amdgcn_mfma_f32_32x32x16_f16(wf0, bf[1][ks], acc[0][1], 0, 0, 0);
            acc[1][0] = __builtin_amdgcn_mfma_f32_32x32x16_f16(wf1, bf[0][ks], acc[1][0], 0, 0, 0);
            acc[1][1] = __builtin_amdgcn_mfma_f32_32x32x16_f16(wf1, bf[1][ks], acc[1][1], 0, 0, 0);
        }
        __builtin_amdgcn_s_setprio(0);

        // ---- issue bf[t+1] (regs free now; cover to step3[t+1]) ----
        if (t < 63) {
            FENCE();
            #pragma unroll
            for (int nd = 0; nd < 2; nd++)
                #pragma unroll
                for (int ks = 0; ks < 4; ks++)
                    bf[nd][ks] = *(const half8*)(xtb + (size_t)(wd0 + nd*32 + m32) * TT
                                                 + (t+1)*64 + ks*16 + h*8);
            FENCE();
        }
        WAITLGKM();
        BAR();   // BAR_D: step3 W reads consumed -> Sred/W writable next tile
    }

    // ---- epilogue: out = x_left * sigmoid(ctx + bias) ----
    const float* xb = x + (size_t)b * TT * 1024;
    float* ob = out + (size_t)b * TT * DH;
    #pragma unroll
    for (int mi2 = 0; mi2 < 2; mi2++)
        #pragma unroll
        for (int nd = 0; nd < 2; nd++) {
            int d = wd0 + nd * 32 + m32;
            float bv = bias[d];
            #pragma unroll
            for (int r = 0; r < 16; r++) {
                int q = q0 + mi2 * 32 + (r & 3) + 8 * (r >> 2) + 4 * h;
                float cv = acc[mi2][nd][r] + bv;
                float gate = 1.0f / (1.0f + __expf(-cv));
                ob[(size_t)q * DH + d] = xb[(size_t)q * 1024 + d] * gate;
            }
        }
}

extern "C" void kernel_launch(void* const* d_in, const int* in_sizes, int n_in,
                              void* d_out, int out_size, void* d_ws, size_t ws_size,
                              hipStream_t stream) {
    const float* x    = (const float*)d_in[0];
    const float* V    = (const float*)d_in[1];
    const float* bias = (const float*)d_in[2];
    float* out = (float*)d_out;

    unsigned short* xn  = (unsigned short*)d_ws;              // [4][4096][512] fp16
    unsigned short* xnT = xn + (size_t)4 * TT * DH;           // [4][512][4096] fp16

    norm_k<<<dim3(4 * TT / 4), 256, 0, stream>>>(x, xn);
    transpose_k<<<dim3(TT / 64, DH / 64, 4), 256, 0, stream>>>(xn, xnT);
    fused_k<<<dim3(TT / 64, 4), 512, 0, stream>>>(xn, xnT, V, bias, x, out);
}

// Round 13
// 198.458 us; speedup vs baseline: 1.5153x; 1.4133x over previous
//
#include <hip/hip_runtime.h>
#include <stdint.h>

typedef _Float16 half8 __attribute__((ext_vector_type(8)));
typedef _Float16 half4v __attribute__((ext_vector_type(4)));
typedef float floatx4 __attribute__((ext_vector_type(4)));
typedef float floatx16 __attribute__((ext_vector_type(16)));

#define TT 4096
#define DH 512

#define WAITLGKM() asm volatile("s_waitcnt lgkmcnt(0)" ::: "memory")
#define BAR() __builtin_amdgcn_s_barrier()
#define FENCE() asm volatile("" ::: "memory")

__device__ __forceinline__ unsigned short f2h(float f) {
    union { _Float16 h; unsigned short u; } v;
    v.h = (_Float16)f;
    return v.u;
}

// ---------- kernel 1: normalize right half of x -> xn (fp16), one wave per row ----------
__global__ void norm_k(const float* __restrict__ x, unsigned short* __restrict__ xn) {
    const int w = threadIdx.x >> 6, l = threadIdx.x & 63;
    const int row = blockIdx.x * 4 + w;              // 0 .. B*T-1
    const float* src = x + (size_t)row * 1024 + 512 + l * 8;
    floatx4 a = *(const floatx4*)src;
    floatx4 c = *(const floatx4*)(src + 4);
    float s = a[0]*a[0] + a[1]*a[1] + a[2]*a[2] + a[3]*a[3]
            + c[0]*c[0] + c[1]*c[1] + c[2]*c[2] + c[3]*c[3];
    #pragma unroll
    for (int off = 32; off > 0; off >>= 1) s += __shfl_xor(s, off);
    const float scale = 1.0f / fmaxf(sqrtf(s), 1e-12f);
    float v[8] = {a[0], a[1], a[2], a[3], c[0], c[1], c[2], c[3]};
    uint32_t pk[4];
    #pragma unroll
    for (int i = 0; i < 4; i++)
        pk[i] = (uint32_t)f2h(v[2*i] * scale) | ((uint32_t)f2h(v[2*i+1] * scale) << 16);
    uint4 o; o.x = pk[0]; o.y = pk[1]; o.z = pk[2]; o.w = pk[3];
    *(uint4*)(xn + (size_t)row * DH + l * 8) = o;
}

// ---------- kernel 2: xnT[b][d][t] = xn[b][t][d], 64x64 LDS tile transpose ----------
__global__ void transpose_k(const unsigned short* __restrict__ xn,
                            unsigned short* __restrict__ xnT) {
    __shared__ __align__(16) unsigned short tile[64 * 72];  // +8 pad
    const int b = blockIdx.z;
    const int t0 = blockIdx.x * 64, d0 = blockIdx.y * 64;
    const int tid = threadIdx.x;
    #pragma unroll
    for (int i = 0; i < 2; i++) {
        int c = i * 256 + tid;
        int tr = c >> 3, d8 = c & 7;
        uint4 vv = *(const uint4*)(xn + ((size_t)(b * TT + t0 + tr) * DH + d0 + d8 * 8));
        *(uint4*)&tile[tr * 72 + d8 * 8] = vv;
    }
    __syncthreads();
    #pragma unroll
    for (int i = 0; i < 2; i++) {
        int c = i * 256 + tid;
        int dd = c >> 3, t8 = c & 7;
        uint32_t pk[4];
        #pragma unroll
        for (int k = 0; k < 4; k++) {
            uint32_t h0 = tile[(t8 * 8 + 2 * k    ) * 72 + dd];
            uint32_t h1 = tile[(t8 * 8 + 2 * k + 1) * 72 + dd];
            pk[k] = h0 | (h1 << 16);
        }
        uint4 o; o.x = pk[0]; o.y = pk[1]; o.z = pk[2]; o.w = pk[3];
        *(uint4*)(xnT + ((size_t)(b * DH + d0 + dd) * TT + t0 + t8 * 8)) = o;
    }
}

// ---------- kernel 3: R6 structure + 3 barriers (own-addr W overlay) + 16-key kn swizzle ----------
// Wave w: step1 role (g=w>>2, mi=(w>>1)&1, dh=w&1): S^T partial p=g*2+dh over K=128;
//   step3/epilogue role: d-slice [w*64, w*64+64).
// Per tile (3 barriers):
//   vmcnt(10) [kn[t] landed; kt[t]+V[t] in flight]
//   step1 (8 rd, 16 mfma, 16-key conflict-free) ; Sred wr ; lgkm ; issue kn[t+1] ; BAR_B
//   reduce (4 rd) ; vmcnt(8) [kt,V landed, kn[t+1] flying] ; *V ;
//   W write to OWN Sred-p0 address (bijection -> no WAR, no barrier) ; lgkm ; BAR_C
//   step3 (8 W rd + 8 kt rd, 16 mfma) ; lgkm ; issue kt[t+1]+V[t+1] ; BAR_D
// LDS 160 KiB exact: kn[8w][32kk][128d] 64K | kt[8w][64d][64kk] 64K | Sred[4][64][64] 32K (p0=W).
__global__ __launch_bounds__(512, 2) void fused_k(
    const unsigned short* __restrict__ xn, const unsigned short* __restrict__ xnT,
    const float* __restrict__ V, const float* __restrict__ bias,
    const float* __restrict__ x, float* __restrict__ out)
{
    __shared__ __align__(16) unsigned short smem[81920];   // 160 KiB exact
    unsigned short* knB   = smem;            // [8 w][32 kk][128 d], chunk16 ^ (row&15)
    unsigned short* ktB   = smem + 32768;    // [8 w][64 d][64 kk], chunk16 ^ (row&7)
    unsigned short* SredL = smem + 65536;    // [4 p][64 q][64 kk]; p0 doubles as W

    const int tid = threadIdx.x;
    const int w = tid >> 6, l = tid & 63;
    const int h = l >> 5, m32 = l & 31;
    const int g = w >> 2, mi = (w >> 1) & 1, dh = w & 1;
    const int p = g * 2 + dh;
    const int wk0 = g * 256 + dh * 128;      // step1 k-range base
    const int wd0 = w * 64;                  // step3 d-slice base

    // XCD-aware swizzle
    const int flat = blockIdx.y * 64 + blockIdx.x;
    const int work = (flat & 7) * 32 + (flat >> 3);
    const int b = work >> 6, qt = work & 63;
    const int q0 = qt * 64;

    const unsigned short* xnb = xn  + (size_t)b * TT * DH;
    const unsigned short* xtb = xnT + (size_t)b * DH * TT;

    unsigned short* knP = knB + w * 4096;
    unsigned short* ktP = ktB + w * 4096;

    // reduce-phase mapping: q-row tq, kk chunk to*8
    const int tq = tid >> 3, to = tid & 7;
    const float* vptr = V + (size_t)(q0 + tq) * TT + to * 8;
    const int rsw = ((to * 2) ^ ((tq & 7) << 1)) * 4;   // Sred phys unit offset (u16)

    // ---- prologue: Q fragments (B-operand): lane q=q0+ni*32+m32, k=wk0+ks*16+h*8+j
    half8 qf[2][8];
    #pragma unroll
    for (int ni = 0; ni < 2; ni++)
        #pragma unroll
        for (int ks = 0; ks < 8; ks++)
            qf[ni][ks] = *(const half8*)(xnb + (size_t)(q0 + ni*32 + m32) * DH
                                         + wk0 + ks*16 + h*8);
    FENCE();
    // stage kn[0]: 8 gll, 4 rows each; 16-key pre-swizzle at source
    #pragma unroll
    for (int i = 0; i < 8; i++) {
        int r = i * 4 + (l >> 4);                        // local kk row 0..31
        int c = (l & 15) ^ (r & 15);                     // pre-swizzled global chunk
        const unsigned short* gp = xnb + (size_t)(mi*32 + r) * DH + wk0 + c * 8;
        __builtin_amdgcn_global_load_lds(
            (const __attribute__((address_space(1))) void*)gp,
            (__attribute__((address_space(3))) void*)&knP[i * 512], 16, 0, 0);
    }
    FENCE();
    // stage kt[0]: 8 gll, 8 d-rows each
    #pragma unroll
    for (int i = 0; i < 8; i++) {
        int dr = i * 8 + (l >> 3);                       // local d row 0..63
        int c = (l & 7) ^ (dr & 7);
        const unsigned short* gp = xtb + (size_t)(wd0 + dr) * TT + c * 8;
        __builtin_amdgcn_global_load_lds(
            (const __attribute__((address_space(1))) void*)gp,
            (__attribute__((address_space(3))) void*)&ktP[i * 512], 16, 0, 0);
    }
    FENCE();
    floatx4 vf0 = *(const floatx4*)(vptr);
    floatx4 vf1 = *(const floatx4*)(vptr + 4);

    floatx16 acc[2][2];
    #pragma unroll
    for (int i = 0; i < 2; i++)
        #pragma unroll
        for (int j = 0; j < 2; j++)
            acc[i][j] = (floatx16)(0.f);

    #pragma unroll 1
    for (int t = 0; t < 64; t++) {
        // ---- kn[t] landed (kt[t] 8 + V[t] 2 stay in flight) ----
        asm volatile("s_waitcnt vmcnt(10)" ::: "memory");

        // ---- step1: S^T partial p, rows mi, k-128; 8 reads (2-way max), 16 mfma ----
        floatx16 s0 = (floatx16)(0.f), s1 = (floatx16)(0.f);
        __builtin_amdgcn_s_setprio(1);
        #pragma unroll
        for (int ks = 0; ks < 8; ks++) {
            half8 a = *(const half8*)&knP[m32 * 128 + (((ks*2 + h) ^ (m32 & 15)) * 8)];
            s0 = __builtin_amdgcn_mfma_f32_32x32x16_f16(a, qf[0][ks], s0, 0, 0, 0);
            s1 = __builtin_amdgcn_mfma_f32_32x32x16_f16(a, qf[1][ks], s1, 0, 0, 0);
        }
        __builtin_amdgcn_s_setprio(0);

        // ---- Sred write: [p][q][phys unit], unit4 ^ ((q&7)<<1) ----
        #pragma unroll
        for (int ni = 0; ni < 2; ni++) {
            const int q = ni * 32 + m32;
            unsigned short* sp = SredL + p * 4096 + q * 64;
            const int sw = (q & 7) << 1;
            #pragma unroll
            for (int rr = 0; rr < 4; rr++) {
                int u = (mi * 8 + rr * 2 + h) ^ sw;
                half4v v4;
                if (ni == 0) {
                    v4[0]=(_Float16)s0[rr*4+0]; v4[1]=(_Float16)s0[rr*4+1];
                    v4[2]=(_Float16)s0[rr*4+2]; v4[3]=(_Float16)s0[rr*4+3];
                } else {
                    v4[0]=(_Float16)s1[rr*4+0]; v4[1]=(_Float16)s1[rr*4+1];
                    v4[2]=(_Float16)s1[rr*4+2]; v4[3]=(_Float16)s1[rr*4+3];
                }
                *(half4v*)&sp[u * 4] = v4;
            }
        }
        WAITLGKM();
        // ---- issue kn[t+1] (private slice consumed; in flight until next vmcnt(10)) ----
        if (t < 63) {
            #pragma unroll
            for (int i = 0; i < 8; i++) {
                int r = i * 4 + (l >> 4);
                int c = (l & 15) ^ (r & 15);
                const unsigned short* gp = xnb + (size_t)((t+1)*64 + mi*32 + r) * DH + wk0 + c * 8;
                __builtin_amdgcn_global_load_lds(
                    (const __attribute__((address_space(1))) void*)gp,
                    (__attribute__((address_space(3))) void*)&knP[i * 512], 16, 0, 0);
            }
            FENCE();
        }
        BAR();   // BAR_B: Sred complete

        // ---- reduce: 4 partials (fp16 adds), *V ----
        half8 pr0 = *(const half8*)&SredL[        tq * 64 + rsw];
        half8 pr1 = *(const half8*)&SredL[4096  + tq * 64 + rsw];
        half8 pr2 = *(const half8*)&SredL[8192  + tq * 64 + rsw];
        half8 pr3 = *(const half8*)&SredL[12288 + tq * 64 + rsw];
        half8 sum = (pr0 + pr1) + (pr2 + pr3);
        if (t < 63) { asm volatile("s_waitcnt vmcnt(8)" ::: "memory"); }
        else        { asm volatile("s_waitcnt vmcnt(0)" ::: "memory"); }
        half8 wv;
        wv[0]=(_Float16)((float)sum[0]*vf0[0]); wv[1]=(_Float16)((float)sum[1]*vf0[1]);
        wv[2]=(_Float16)((float)sum[2]*vf0[2]); wv[3]=(_Float16)((float)sum[3]*vf0[3]);
        wv[4]=(_Float16)((float)sum[4]*vf1[0]); wv[5]=(_Float16)((float)sum[5]*vf1[1]);
        wv[6]=(_Float16)((float)sum[6]*vf1[2]); wv[7]=(_Float16)((float)sum[7]*vf1[3]);
        // ---- W write to OWN Sred-p0 address (read-then-write same 16B; no WAR) ----
        *(half8*)&SredL[tq * 64 + rsw] = wv;
        WAITLGKM();
        BAR();   // BAR_C: W ready (all threads wrote their own slot)

        // ---- step3: ctx[q][wd0..+64] += W * Kn ; 16 reads, 16 mfma ----
        __builtin_amdgcn_s_setprio(1);
        #pragma unroll
        for (int ks = 0; ks < 4; ks++) {
            const int wu = ((ks*4 + h*2) ^ ((m32 & 7) << 1)) * 4;
            half8 wf0 = *(const half8*)&SredL[(m32     ) * 64 + wu];
            half8 wf1 = *(const half8*)&SredL[(32 + m32) * 64 + wu];
            const int ko = ((ks*2 + h) ^ (m32 & 7)) * 8;
            half8 kf0 = *(const half8*)&ktP[(m32     ) * 64 + ko];
            half8 kf1 = *(const half8*)&ktP[(32 + m32) * 64 + ko];
            acc[0][0] = __builtin_amdgcn_mfma_f32_32x32x16_f16(wf0, kf0, acc[0][0], 0, 0, 0);
            acc[0][1] = __builtin_amdgcn_mfma_f32_32x32x16_f16(wf0, kf1, acc[0][1], 0, 0, 0);
            acc[1][0] = __builtin_amdgcn_mfma_f32_32x32x16_f16(wf1, kf0, acc[1][0], 0, 0, 0);
            acc[1][1] = __builtin_amdgcn_mfma_f32_32x32x16_f16(wf1, kf1, acc[1][1], 0, 0, 0);
        }
        __builtin_amdgcn_s_setprio(0);
        WAITLGKM();
        // ---- issue kt[t+1] + V[t+1] (private; cover = next step1+reduce) ----
        if (t < 63) {
            #pragma unroll
            for (int i = 0; i < 8; i++) {
                int dr = i * 8 + (l >> 3);
                int c = (l & 7) ^ (dr & 7);
                const unsigned short* gp = xtb + (size_t)(wd0 + dr) * TT + (t+1)*64 + c * 8;
                __builtin_amdgcn_global_load_lds(
                    (const __attribute__((address_space(1))) void*)gp,
                    (__attribute__((address_space(3))) void*)&ktP[i * 512], 16, 0, 0);
            }
            FENCE();
            vf0 = *(const floatx4*)(vptr + (t+1)*64);
            vf1 = *(const floatx4*)(vptr + (t+1)*64 + 4);
            FENCE();
        }
        BAR();   // BAR_D: step3 reads done -> Sred/W reusable next tile
    }

    // ---- epilogue: out = x_left * sigmoid(ctx + bias) ----
    const float* xb = x + (size_t)b * TT * 1024;
    float* ob = out + (size_t)b * TT * DH;
    #pragma unroll
    for (int mi2 = 0; mi2 < 2; mi2++)
        #pragma unroll
        for (int nd = 0; nd < 2; nd++) {
            int d = wd0 + nd * 32 + m32;
            float bv = bias[d];
            #pragma unroll
            for (int r = 0; r < 16; r++) {
                int q = q0 + mi2 * 32 + (r & 3) + 8 * (r >> 2) + 4 * h;
                float cv = acc[mi2][nd][r] + bv;
                float gate = 1.0f / (1.0f + __expf(-cv));
                ob[(size_t)q * DH + d] = xb[(size_t)q * 1024 + d] * gate;
            }
        }
}

extern "C" void kernel_launch(void* const* d_in, const int* in_sizes, int n_in,
                              void* d_out, int out_size, void* d_ws, size_t ws_size,
                              hipStream_t stream) {
    const float* x    = (const float*)d_in[0];
    const float* V    = (const float*)d_in[1];
    const float* bias = (const float*)d_in[2];
    float* out = (float*)d_out;

    unsigned short* xn  = (unsigned short*)d_ws;              // [4][4096][512] fp16
    unsigned short* xnT = xn + (size_t)4 * TT * DH;           // [4][512][4096] fp16

    norm_k<<<dim3(4 * TT / 4), 256, 0, stream>>>(x, xn);
    transpose_k<<<dim3(TT / 64, DH / 64, 4), 256, 0, stream>>>(xn, xnT);
    fused_k<<<dim3(TT / 64, 4), 512, 0, stream>>>(xn, xnT, V, bias, x, out);
}